// Round 1
// 420.140 us; speedup vs baseline: 1.0382x; 1.0382x over previous
//
#include <hip/hip_runtime.h>
#include <hip/hip_bf16.h>

// GCN forward, bf16-MFMA + bf16 intermediates + XCD m-striping + BK=64 XOR-swizzle.
//   H1 = F @ W1                  (bf16 MFMA, bf16 out, stride 1008)
//   X1 = relu(agg(H1)+b1)        (bf16 gather-agg, bf16 out padded to 1024)
//   H2 = X1 @ W2                 (bf16 MFMA, bf16 out, stride 504)
//   out = relu(relu(agg(H2)+b2) @ W3 + b3)   (fused agg+layer3)
// R1: multi-block CSR scan (was single-block serial), count_deg fused into
//     cast, agg1 8-deep gather unroll, agg2_out 64-lane x 16B gather.

#define N_NODES 20000
#define N_EDGES 200000
#define D_IN    1433
#define D_H1    1000
#define D_H2    500
#define D_OUT   7

#define MPAD    20096        // 157 * 128
#define K1PAD   1472         // D_IN padded to mult of 64
#define N1PAD   1024
#define K2PAD   1024
#define N2PAD   512
#define H1STR   1008
#define H2STR   504
#define MBLK    157          // m-blocks of 128
#define SCAN_N  (N_NODES + 1)
#define SCAN_NB 20           // ceil(20001 / 1024)

typedef __attribute__((ext_vector_type(8))) short short8;
typedef __attribute__((ext_vector_type(8))) unsigned short ushort8_t;
typedef __attribute__((ext_vector_type(4))) float f32x4;

__device__ __forceinline__ unsigned short bf16_rne(float x) {
    unsigned int u = __float_as_uint(x);
    u = (u + 0x7FFFu + ((u >> 16) & 1u)) >> 16;
    return (unsigned short)u;
}
__device__ __forceinline__ float bf16_up(unsigned short h) {
    return __uint_as_float((unsigned int)h << 16);
}

__device__ __forceinline__ void gl_lds16(const unsigned short* g, unsigned short* lds) {
    __builtin_amdgcn_global_load_lds(
        (const __attribute__((address_space(1))) unsigned int*)g,
        (__attribute__((address_space(3))) unsigned int*)lds, 16, 0, 0);
}

// ------------------------------------------- fused cast + degree count
// grid = MPAD blocks; blocks 0..781 additionally count one edge per thread.
// Atomics on offs[] hide under the cast's HBM traffic; saves a launch.
__global__ __launch_bounds__(256) void cast_count(const float* __restrict__ F,
                                                  unsigned int* __restrict__ out,
                                                  const int* __restrict__ dst,
                                                  int* __restrict__ offs) {
    int row = blockIdx.x;
    int t = threadIdx.x;
    int e = row * 256 + t;
    if (e < N_EDGES) atomicAdd(&offs[dst[e] + 1], 1);
    const float* fr = F + (size_t)row * D_IN;
    bool live = row < N_NODES;
    for (int kk = t; kk < K1PAD / 2; kk += 256) {
        int k0 = kk * 2;
        float a = (live && k0     < D_IN) ? fr[k0]     : 0.f;
        float b = (live && k0 + 1 < D_IN) ? fr[k0 + 1] : 0.f;
        out[(size_t)row * (K1PAD / 2) + kk] =
            (unsigned int)bf16_rne(a) | ((unsigned int)bf16_rne(b) << 16);
    }
}

// ------------------------------------------- multi-block inclusive scan
// pass 1: each of SCAN_NB blocks scans its 1024-elem slice, emits block sum
__global__ __launch_bounds__(1024) void scan_part(int* __restrict__ offs,
                                                  int* __restrict__ bsum) {
    __shared__ int wsum[16];
    const int t = threadIdx.x, lane = t & 63, wv = t >> 6;
    int i = blockIdx.x * 1024 + t;
    int v = (i < SCAN_N) ? offs[i] : 0;
    #pragma unroll
    for (int s = 1; s < 64; s <<= 1) {
        int u = __shfl_up(v, s, 64);
        if (lane >= s) v += u;
    }
    if (lane == 63) wsum[wv] = v;
    __syncthreads();
    int prefix = 0;
    for (int k = 0; k < wv; ++k) prefix += wsum[k];
    v += prefix;
    if (i < SCAN_N) offs[i] = v;
    if (t == 1023) bsum[blockIdx.x] = v;
}

// pass 2: single wave scans the SCAN_NB block sums
__global__ __launch_bounds__(64) void scan_sums(int* __restrict__ bsum) {
    const int t = threadIdx.x;
    int v = (t < SCAN_NB) ? bsum[t] : 0;
    #pragma unroll
    for (int s = 1; s < 64; s <<= 1) {
        int u = __shfl_up(v, s, 64);
        if (t >= s) v += u;
    }
    if (t < SCAN_NB) bsum[t] = v;
}

// pass 3: add exclusive block prefix; fill cursor[i] = offs[i]
__global__ __launch_bounds__(1024) void scan_add(int* __restrict__ offs,
                                                 const int* __restrict__ bsum,
                                                 int* __restrict__ cursor) {
    int blk = blockIdx.x;
    int i = blk * 1024 + threadIdx.x;
    int add = blk ? bsum[blk - 1] : 0;
    if (i < SCAN_N) {
        int v = offs[i] + add;
        offs[i] = v;
        if (i < N_NODES) cursor[i] = v;
    }
}

__global__ __launch_bounds__(256) void fill_csr(const int* __restrict__ src,
                                                const int* __restrict__ dst,
                                                int* __restrict__ cursor,
                                                int* __restrict__ srcs) {
    int e = blockIdx.x * 256 + threadIdx.x;
    if (e < N_EDGES) {
        int pos = atomicAdd(&cursor[dst[e]], 1);
        srcs[pos] = src[e];
    }
}

// --------------------------------------------------------------- weight casts
template <int SR, int SC, int DR, int DC>
__global__ __launch_bounds__(256) void transpose_cast_pad(const float* __restrict__ src,
                                                          unsigned short* __restrict__ dst) {
    __shared__ float tile[32][33];
    int c0 = blockIdx.x * 32;
    int r0 = blockIdx.y * 32;
    int tx = threadIdx.x & 31, ty = threadIdx.x >> 5;
    #pragma unroll
    for (int p = 0; p < 4; ++p) {
        int r = r0 + ty + p * 8, c = c0 + tx;
        tile[ty + p * 8][tx] = (r < SR && c < SC) ? src[(size_t)r * SC + c] : 0.f;
    }
    __syncthreads();
    #pragma unroll
    for (int p = 0; p < 4; ++p) {
        int dr = c0 + ty + p * 8;
        int dc = r0 + tx;
        if (dr < DR && dc < DC) dst[(size_t)dr * DC + dc] = bf16_rne(tile[tx][ty + p * 8]);
    }
}

// -------------------------------------------------------------- bf16 MFMA GEMM
// C[M,N](bf16, stride OSTR) = A[MPAD,KPAD] @ B^T rows[NPAD,KPAD].
// XCD m-striping: xcd = bid&7 owns m-blocks {xcd, xcd+8, ...} -> A fetched once
// chip-wide. Single LDS buffer, BK=64, 8-slot XOR swizzle (see prev session).
// C-write covers pad columns up to OSTR (B pad rows are zero -> acc==0 there),
// so downstream 16B gathers may read [0,OSTR) without masking.
template <int KPAD, int NB>
__global__ __launch_bounds__(256) void gemm_mfma(const unsigned short* __restrict__ A,
                                                 const unsigned short* __restrict__ B,
                                                 unsigned short* __restrict__ C,
                                                 int M, int OSTR) {
    __shared__ __align__(16) unsigned short sA[128 * 64];
    __shared__ __align__(16) unsigned short sB[128 * 64];
    const int bid = blockIdx.x;
    const int xcd = bid & 7;
    const int tt  = bid >> 3;
    const int nb  = tt % NB;
    const int mb  = (tt / NB) * 8 + xcd;
    if (mb >= MBLK) return;

    const int t = threadIdx.x;
    const int w = t >> 6, lane = t & 63;
    const int m0 = mb * 128, n0 = nb * 128;
    const int wm = (w >> 1) * 64, wn = (w & 1) * 64;

    const int srowo = lane >> 3;                       // row offset in 8-row group
    const int skc   = ((lane & 7) ^ srowo) * 8;        // XOR-swizzled global k-chunk
    const int mrow = lane & 15, quad = lane >> 4;

    const unsigned short* Aptr = A + (size_t)(m0 + srowo) * KPAD + skc;
    const unsigned short* Bptr = B + (size_t)(n0 + srowo) * KPAD + skc;

    f32x4 acc[4][4] = {};

    for (int k0 = 0; k0 < KPAD; k0 += 64) {
        #pragma unroll
        for (int c = 0; c < 4; ++c) {
            const int rbase = c * 32 + w * 8;          // 8-aligned
            gl_lds16(Aptr + (size_t)rbase * KPAD, &sA[rbase * 64]);
            gl_lds16(Bptr + (size_t)rbase * KPAD, &sB[rbase * 64]);
        }
        Aptr += 64; Bptr += 64;
        __syncthreads();

        #pragma unroll
        for (int s = 0; s < 2; ++s) {
            short8 af[4], bf[4];
            #pragma unroll
            for (int mt = 0; mt < 4; ++mt) {
                int r = wm + mt * 16 + mrow;
                af[mt] = *(const short8*)&sA[r * 64 + (((s * 4 + quad) ^ (mrow & 7)) * 8)];
            }
            #pragma unroll
            for (int nt = 0; nt < 4; ++nt) {
                int r = wn + nt * 16 + mrow;
                bf[nt] = *(const short8*)&sB[r * 64 + (((s * 4 + quad) ^ (mrow & 7)) * 8)];
            }
            #pragma unroll
            for (int mt = 0; mt < 4; ++mt)
                #pragma unroll
                for (int nt = 0; nt < 4; ++nt)
                    acc[mt][nt] = __builtin_amdgcn_mfma_f32_16x16x32_bf16(
                        af[mt], bf[nt], acc[mt][nt], 0, 0, 0);
        }
        __syncthreads();
    }

    // C/D layout: col = lane&15, row = quad*4 + reg
    #pragma unroll
    for (int mt = 0; mt < 4; ++mt) {
        int m = m0 + wm + mt * 16 + quad * 4;
        #pragma unroll
        for (int nt = 0; nt < 4; ++nt) {
            int n = n0 + wn + nt * 16 + mrow;
            if (n >= OSTR) continue;
            #pragma unroll
            for (int r = 0; r < 4; ++r)
                if (m + r < M) C[(size_t)(m + r) * OSTR + n] = bf16_rne(acc[mt][nt][r]);
        }
    }
}

// -------------------------------- agg1: X1 = relu(agg(H1)+b1), bf16 -> bf16
// grid = MPAD: blocks >= N_NODES emit zero pad rows. 8-deep edge unroll keeps
// 8 independent 16B gathers in flight per lane (latency-bound L3 reads).
__global__ __launch_bounds__(128) void agg1_bf16(const unsigned short* __restrict__ H,
                                                 const int* __restrict__ offs,
                                                 const int* __restrict__ srcs,
                                                 const float* __restrict__ bias,
                                                 unsigned short* __restrict__ X) {
    const int i = blockIdx.x, t = threadIdx.x;
    const bool active = t < 125;
    const int tc = active ? t : 124;
    ushort8_t o = (ushort8_t)0;
    if (i < N_NODES) {
        const int beg = offs[i], end = offs[i + 1];
        const unsigned short* Hc = H + tc * 8;
        float s[8] = {};
        int e = beg;
        for (; e + 8 <= end; e += 8) {
            int j0 = srcs[e],     j1 = srcs[e + 1], j2 = srcs[e + 2], j3 = srcs[e + 3];
            int j4 = srcs[e + 4], j5 = srcs[e + 5], j6 = srcs[e + 6], j7 = srcs[e + 7];
            ushort8_t v0 = *(const ushort8_t*)(Hc + (size_t)j0 * H1STR);
            ushort8_t v1 = *(const ushort8_t*)(Hc + (size_t)j1 * H1STR);
            ushort8_t v2 = *(const ushort8_t*)(Hc + (size_t)j2 * H1STR);
            ushort8_t v3 = *(const ushort8_t*)(Hc + (size_t)j3 * H1STR);
            ushort8_t v4 = *(const ushort8_t*)(Hc + (size_t)j4 * H1STR);
            ushort8_t v5 = *(const ushort8_t*)(Hc + (size_t)j5 * H1STR);
            ushort8_t v6 = *(const ushort8_t*)(Hc + (size_t)j6 * H1STR);
            ushort8_t v7 = *(const ushort8_t*)(Hc + (size_t)j7 * H1STR);
            #pragma unroll
            for (int u = 0; u < 8; ++u) {
                float t0 = (bf16_up(v0[u]) + bf16_up(v1[u])) +
                           (bf16_up(v2[u]) + bf16_up(v3[u]));
                float t1 = (bf16_up(v4[u]) + bf16_up(v5[u])) +
                           (bf16_up(v6[u]) + bf16_up(v7[u]));
                s[u] += t0 + t1;
            }
        }
        for (; e + 4 <= end; e += 4) {
            int j0 = srcs[e], j1 = srcs[e + 1], j2 = srcs[e + 2], j3 = srcs[e + 3];
            ushort8_t v0 = *(const ushort8_t*)(Hc + (size_t)j0 * H1STR);
            ushort8_t v1 = *(const ushort8_t*)(Hc + (size_t)j1 * H1STR);
            ushort8_t v2 = *(const ushort8_t*)(Hc + (size_t)j2 * H1STR);
            ushort8_t v3 = *(const ushort8_t*)(Hc + (size_t)j3 * H1STR);
            #pragma unroll
            for (int u = 0; u < 8; ++u)
                s[u] += (bf16_up(v0[u]) + bf16_up(v1[u])) +
                        (bf16_up(v2[u]) + bf16_up(v3[u]));
        }
        for (; e < end; ++e) {
            ushort8_t v = *(const ushort8_t*)(Hc + (size_t)srcs[e] * H1STR);
            #pragma unroll
            for (int u = 0; u < 8; ++u) s[u] += bf16_up(v[u]);
        }
        if (active) {
            #pragma unroll
            for (int u = 0; u < 8; ++u)
                o[u] = bf16_rne(fmaxf(s[u] + bias[t * 8 + u], 0.f));
        }
    }
    *(ushort8_t*)(X + (size_t)i * K2PAD + t * 8) = o;
}

// ---------------- agg2 + layer3: out = relu(relu(agg(H2)+b2) @ W3 + b3)
// 64 lanes x 16B gather (was 128 x 8B): half the load instructions per edge.
// Lane t covers cols [8t, 8t+8); lane 62 spans cols 496..503 (500..503 are
// zeroed pad written by gemm2); lane 63 clamps to 62 (coalesces, contributes 0).
__global__ __launch_bounds__(64) void agg2_out(const unsigned short* __restrict__ H,
                                               const int* __restrict__ offs,
                                               const int* __restrict__ srcs,
                                               const float* __restrict__ b2,
                                               const float* __restrict__ W3,
                                               const float* __restrict__ b3,
                                               float* __restrict__ out) {
    const int i = blockIdx.x, t = threadIdx.x;
    const int tc = t < 63 ? t : 62;
    const int beg = offs[i], end = offs[i + 1];
    const unsigned short* Hc = H + tc * 8;
    float s[8] = {};
    int e = beg;
    for (; e + 8 <= end; e += 8) {
        int j0 = srcs[e],     j1 = srcs[e + 1], j2 = srcs[e + 2], j3 = srcs[e + 3];
        int j4 = srcs[e + 4], j5 = srcs[e + 5], j6 = srcs[e + 6], j7 = srcs[e + 7];
        ushort8_t v0 = *(const ushort8_t*)(Hc + (size_t)j0 * H2STR);
        ushort8_t v1 = *(const ushort8_t*)(Hc + (size_t)j1 * H2STR);
        ushort8_t v2 = *(const ushort8_t*)(Hc + (size_t)j2 * H2STR);
        ushort8_t v3 = *(const ushort8_t*)(Hc + (size_t)j3 * H2STR);
        ushort8_t v4 = *(const ushort8_t*)(Hc + (size_t)j4 * H2STR);
        ushort8_t v5 = *(const ushort8_t*)(Hc + (size_t)j5 * H2STR);
        ushort8_t v6 = *(const ushort8_t*)(Hc + (size_t)j6 * H2STR);
        ushort8_t v7 = *(const ushort8_t*)(Hc + (size_t)j7 * H2STR);
        #pragma unroll
        for (int u = 0; u < 8; ++u) {
            float t0 = (bf16_up(v0[u]) + bf16_up(v1[u])) +
                       (bf16_up(v2[u]) + bf16_up(v3[u]));
            float t1 = (bf16_up(v4[u]) + bf16_up(v5[u])) +
                       (bf16_up(v6[u]) + bf16_up(v7[u]));
            s[u] += t0 + t1;
        }
    }
    for (; e + 4 <= end; e += 4) {
        int j0 = srcs[e], j1 = srcs[e + 1], j2 = srcs[e + 2], j3 = srcs[e + 3];
        ushort8_t v0 = *(const ushort8_t*)(Hc + (size_t)j0 * H2STR);
        ushort8_t v1 = *(const ushort8_t*)(Hc + (size_t)j1 * H2STR);
        ushort8_t v2 = *(const ushort8_t*)(Hc + (size_t)j2 * H2STR);
        ushort8_t v3 = *(const ushort8_t*)(Hc + (size_t)j3 * H2STR);
        #pragma unroll
        for (int u = 0; u < 8; ++u)
            s[u] += (bf16_up(v0[u]) + bf16_up(v1[u])) +
                    (bf16_up(v2[u]) + bf16_up(v3[u]));
    }
    for (; e < end; ++e) {
        ushort8_t v = *(const ushort8_t*)(Hc + (size_t)srcs[e] * H2STR);
        #pragma unroll
        for (int u = 0; u < 8; ++u) s[u] += bf16_up(v[u]);
    }

    float acc[D_OUT] = {};
    if (t < 63) {
        #pragma unroll
        for (int u = 0; u < 8; ++u) {
            int col = t * 8 + u;
            if (col < D_H2) {
                float x = fmaxf(s[u] + b2[col], 0.f);
                const float* wr = W3 + (size_t)col * D_OUT;
                #pragma unroll
                for (int j = 0; j < D_OUT; ++j) acc[j] += x * wr[j];
            }
        }
    }
    #pragma unroll
    for (int j = 0; j < D_OUT; ++j)
        #pragma unroll
        for (int off = 32; off; off >>= 1) acc[j] += __shfl_down(acc[j], off);
    if (t == 0) {
        #pragma unroll
        for (int j = 0; j < D_OUT; ++j)
            out[(size_t)i * D_OUT + j] = fmaxf(acc[j] + b3[j], 0.f);
    }
}

// ---------------------------------------------------------------------- launch
extern "C" void kernel_launch(void* const* d_in, const int* in_sizes, int n_in,
                              void* d_out, int out_size, void* d_ws, size_t ws_size,
                              hipStream_t stream) {
    const float* features = (const float*)d_in[0];
    const int*   src      = (const int*)d_in[1];
    const int*   dst      = (const int*)d_in[2];
    const float* W1       = (const float*)d_in[3];
    const float* b1       = (const float*)d_in[4];
    const float* W2       = (const float*)d_in[5];
    const float* b2       = (const float*)d_in[6];
    const float* W3       = (const float*)d_in[7];
    const float* b3       = (const float*)d_in[8];
    float* out = (float*)d_out;

    char* ws = (char*)d_ws;
    unsigned short* Fbf  = (unsigned short*)(ws + 0);          // [MPAD][K1PAD]  59,162,624 B
    unsigned short* X1bf = (unsigned short*)(ws + 0);          // [MPAD][K2PAD]  41,156,608 B (overlay)
    unsigned short* H1   = (unsigned short*)(ws + 59162624);   // [20000][H1STR] 40,320,000 B
    unsigned short* H2   = (unsigned short*)(ws + 59162624);   // [20000][H2STR] 20,160,000 B (overlay)
    unsigned short* W1T  = (unsigned short*)(ws + 99482624);   // [N1PAD][K1PAD]  3,014,656 B
    unsigned short* W2T  = (unsigned short*)(ws + 102497280);  // [N2PAD][K2PAD]  1,048,576 B
    int* offs   = (int*)(ws + 103545856);                      // [N_NODES+1]
    int* cursor = (int*)(ws + 103625984);                      // [20000] (+32 spare ints)
    int* srcs   = (int*)(ws + 103706112);                      // [N_EDGES]
    int* bsum   = cursor + N_NODES;                            // 20 ints in the spare gap

    // ---- CSR build (count fused into cast below)
    hipMemsetAsync(offs, 0, (N_NODES + 1) * sizeof(int), stream);

    // ---- cast + degree count
    cast_count<<<MPAD, 256, 0, stream>>>(features, (unsigned int*)Fbf, dst, offs);
    transpose_cast_pad<D_IN, D_H1, N1PAD, K1PAD>
        <<<dim3(N1PAD / 32, K1PAD / 32), 256, 0, stream>>>(W1, W1T);
    transpose_cast_pad<D_H1, D_H2, N2PAD, K2PAD>
        <<<dim3(N2PAD / 32, K2PAD / 32), 256, 0, stream>>>(W2, W2T);

    // ---- CSR scan (multi-block) + fill
    scan_part<<<SCAN_NB, 1024, 0, stream>>>(offs, bsum);
    scan_sums<<<1, 64, 0, stream>>>(bsum);
    scan_add<<<SCAN_NB, 1024, 0, stream>>>(offs, bsum, cursor);
    fill_csr<<<(N_EDGES + 255) / 256, 256, 0, stream>>>(src, dst, cursor, srcs);

    // ---- layer 1: H1 = F @ W1; X1 = relu(agg(H1)+b1) (pad rows zeroed in-kernel)
    gemm_mfma<K1PAD, N1PAD / 128><<<8 * (N1PAD / 128) * 20, 256, 0, stream>>>(
        Fbf, W1T, H1, N_NODES, H1STR);
    agg1_bf16<<<MPAD, 128, 0, stream>>>(H1, offs, srcs, b1, X1bf);

    // ---- layer 2: H2 = X1 @ W2; out = fused agg2 + layer3
    gemm_mfma<K2PAD, N2PAD / 128><<<8 * (N2PAD / 128) * 20, 256, 0, stream>>>(
        X1bf, W2T, H2, N_NODES, H2STR);
    agg2_out<<<N_NODES, 64, 0, stream>>>(H2, offs, srcs, b2, W3, b3, out);
}